// Round 2
// baseline (110.440 us; speedup 1.0000x reference)
//
#include <hip/hip_runtime.h>

// Gated CRF 3D->2D loss, round 8: single-kernel fused reduction.
// Round 7 (batched branchless gather) kept; the separate 1-block
// reduce_partials kernel is replaced by a last-block-done reduction:
//   - every block stores its partial (release/agent) and bumps a
//     counter (acq_rel/agent);
//   - the block seeing old==NBLOCKS-1 replays the EXACT summation
//     order of the old reduce kernel (bitwise-identical result);
//   - counter is zeroed by a 4-byte hipMemsetAsync before the kernel
//     (workspace is poisoned each iteration, so it must be re-zeroed).
// Removes one kernel node + its gap + the serial 1-block tail.

constexpr int N = 2, H = 64, W = 64, D = 64, R = 3;
constexpr int WD  = W * D;
constexpr int HWD = H * W * D;
constexpr float INV_SXY  = 1.0f / 6.0f;
constexpr float LOG2E    = 1.4426950408889634f;
constexpr float C2       = 50.0f * LOG2E;   // 0.5*(1/0.1)^2 * log2(e)
constexpr int GBLOCKS = N * H * (W / 16);   // 512 spatial blocks
constexpr int NBLOCKS = 4 * GBLOCKS;        // x4 offset groups = 2048

__device__ __forceinline__ float exp2_fast(float x) {
    return __builtin_amdgcn_exp2f(x);       // v_exp_f32
}

// One offset group: 6 pairs, fully unrolled, loads batched before compute.
template <int DI0, int DJ0, int DI1, int DJ1, int DI2, int DJ2,
          int DI3, int DJ3, int DI4, int DJ4, int DI5, int DJ5>
__device__ __forceinline__ float group_sum(
    const float* __restrict__ sb, const float* __restrict__ y0b,
    int cidx, int h, int w,
    const float scv[4], const float bv[4]) {
    constexpr int DI[6] = {DI0, DI1, DI2, DI3, DI4, DI5};
    constexpr int DJ[6] = {DJ0, DJ1, DJ2, DJ3, DJ4, DJ5};

    bool   vld[6];
    float4 sn[6], an[6];

    // Phase 1: addresses + all 12 loads, no control flow in between.
    #pragma unroll
    for (int p = 0; p < 6; ++p) {
        const bool v = ((unsigned)(h + DI[p]) < (unsigned)H) &
                       ((unsigned)(w + DJ[p]) < (unsigned)W);
        vld[p] = v;
        const int off = v ? (DI[p] * WD + DJ[p] * D) : 0;  // clamp -> center
        sn[p] = *(const float4*)(sb  + cidx + off);
        an[p] = *(const float4*)(y0b + cidx + off);
    }

    // Phase 2: compute. Invalid pairs get A2 = -1e30 -> exp2 -> 0.
    float acc = 0.0f;
    #pragma unroll
    for (int p = 0; p < 6; ++p) {
        constexpr float d2[6] = {
            (float)(DI0 * DI0 + DJ0 * DJ0), (float)(DI1 * DI1 + DJ1 * DJ1),
            (float)(DI2 * DI2 + DJ2 * DJ2), (float)(DI3 * DI3 + DJ3 * DJ3),
            (float)(DI4 * DI4 + DJ4 * DJ4), (float)(DI5 * DI5 + DJ5 * DJ5)};
        const float A2  = -0.5f * d2[p] * (INV_SXY * INV_SXY) * LOG2E;
        const float A2e = vld[p] ? A2 : -1e30f;
        const float snv[4] = {sn[p].x, sn[p].y, sn[p].z, sn[p].w};
        const float anv[4] = {an[p].x, an[p].y, an[p].z, an[p].w};
        #pragma unroll
        for (int j = 0; j < 4; ++j) {
            const float dsr = snv[j] - scv[j];
            const float k   = exp2_fast(__builtin_fmaf(-C2 * dsr, dsr, A2e));
            const float ab  = anv[j] * bv[j];
            acc += k * (anv[j] + bv[j] - 2.0f * ab);
        }
    }
    return acc;
}

__global__ __launch_bounds__(256) void crf_fused(
    const float* __restrict__ y,   // (N,2,H,W,D) -- only channel 0 read
    const float* __restrict__ s,   // (N,1,H,W,D)
    float* __restrict__ partial,   // NBLOCKS floats in workspace
    unsigned* __restrict__ counter, // 1 uint in workspace, pre-zeroed
    float* __restrict__ out) {
    const int tid   = threadIdx.x;
    const int d0    = (tid & 15) << 2;
    const int wlane = tid >> 4;
    const int bid   = blockIdx.x;
    const int sbid  = bid & (GBLOCKS - 1);
    const int g     = bid >> 9;            // offset group 0..3
    const int w = ((sbid & 3) << 4) + wlane;
    const int h = (sbid >> 2) & 63;
    const int n = sbid >> 8;

    const float* sb  = s + (size_t)n * HWD;
    const float* y0b = y + (size_t)n * (2 * HWD);

    const int cidx = h * WD + w * D + d0;
    const float4 sc4 = *(const float4*)(sb  + cidx);
    const float4 b4  = *(const float4*)(y0b + cidx);
    const float scv[4] = {sc4.x, sc4.y, sc4.z, sc4.w};
    const float bv[4]  = {b4.x,  b4.y,  b4.z,  b4.w};

    float acc = 0.0f;
    float extra = 0.0f;
    if (g == 0) {
        acc = group_sum<0, 1, 0, 2, 0, 3, 1, -3, 1, -2, 1, -1>(
            sb, y0b, cidx, h, w, scv, bv);
        // OOB closed form (window truncation), group 0 only.
        const int nrows = min(h + R, H - 1) - max(h - R, 0) + 1;
        const int ncols = min(w + R, W - 1) - max(w - R, 0) + 1;
        const int oob = 49 - nrows * ncols;
        if (oob) {
            const float fh = (float)h * INV_SXY;
            const float fw = (float)w * INV_SXY;
            const float base2 = -0.5f * (fh * fh + fw * fw) * LOG2E;
            float koob = 0.0f;
            #pragma unroll
            for (int j = 0; j < 4; ++j)
                koob += exp2_fast(__builtin_fmaf(-C2 * scv[j], scv[j], base2));
            extra = (float)oob * koob;
        }
    } else if (g == 1) {
        acc = group_sum<1, 0, 1, 1, 1, 2, 1, 3, 2, -3, 2, -2>(
            sb, y0b, cidx, h, w, scv, bv);
    } else if (g == 2) {
        acc = group_sum<2, -1, 2, 0, 2, 1, 2, 2, 2, 3, 3, -3>(
            sb, y0b, cidx, h, w, scv, bv);
    } else {
        acc = group_sum<3, -2, 3, -1, 3, 0, 3, 1, 3, 2, 3, 3>(
            sb, y0b, cidx, h, w, scv, bv);
    }

    float part = 2.0f * acc + extra;

    #pragma unroll
    for (int off = 32; off; off >>= 1)
        part += __shfl_down(part, off, 64);

    __shared__ float wsum[4];
    __shared__ int lastflag;
    if ((tid & 63) == 0) wsum[tid >> 6] = part;
    __syncthreads();

    if (tid == 0) {
        const float blocksum = wsum[0] + wsum[1] + wsum[2] + wsum[3];
        __hip_atomic_store(&partial[bid], blocksum,
                           __ATOMIC_RELEASE, __HIP_MEMORY_SCOPE_AGENT);
        const unsigned old = __hip_atomic_fetch_add(
            counter, 1u, __ATOMIC_ACQ_REL, __HIP_MEMORY_SCOPE_AGENT);
        lastflag = (old == (unsigned)(NBLOCKS - 1));
    }
    __syncthreads();

    if (lastflag) {
        // Replay the exact summation order of the old reduce_partials
        // kernel -> bitwise-identical final value.
        float v = 0.0f;
        #pragma unroll
        for (int i = 0; i < NBLOCKS / 256; ++i)
            v += __hip_atomic_load(&partial[tid + i * 256],
                                   __ATOMIC_RELAXED, __HIP_MEMORY_SCOPE_AGENT);
        #pragma unroll
        for (int off = 32; off; off >>= 1)
            v += __shfl_down(v, off, 64);
        __syncthreads();                    // wsum reuse hazard
        if ((tid & 63) == 0) wsum[tid >> 6] = v;
        __syncthreads();
        if (tid == 0)
            out[0] = (wsum[0] + wsum[1] + wsum[2] + wsum[3]) *
                     (1.0f / (float)(N * D * H * W));
    }
}

extern "C" void kernel_launch(void* const* d_in, const int* in_sizes, int n_in,
                              void* d_out, int out_size, void* d_ws, size_t ws_size,
                              hipStream_t stream) {
    const float* y = (const float*)d_in[0];
    const float* s = (const float*)d_in[1];
    float* partial = (float*)d_ws;                    // NBLOCKS floats
    unsigned* counter = (unsigned*)((char*)d_ws + NBLOCKS * sizeof(float));

    // Workspace is poisoned each iteration: re-zero the 4-byte counter.
    hipMemsetAsync(counter, 0, sizeof(unsigned), stream);
    crf_fused<<<dim3(NBLOCKS), dim3(256), 0, stream>>>(
        y, s, partial, counter, (float*)d_out);
}

// Round 3
// 62.679 us; speedup vs baseline: 1.7620x; 1.7620x over previous
//
#include <hip/hip_runtime.h>

// Gated CRF 3D->2D loss, round 9: XCD-slab swizzle.
// Round 7 two-kernel structure restored (round 8's last-block atomic
// reduction cost ~50us: same-address acq_rel agent atomics serialize).
// New: block->XCD remap. Dispatcher round-robins blockIdx across the 8
// XCDs (xcd = bid & 7); we assign each XCD a contiguous h-slab of 8 rows
// (+3 halo) so its 256 resident blocks share a ~720 KB working set that
// fits the 4 MiB per-XCD L2. Without this, every XCD demands the full
// 6 MB input at once -> L2 capacity thrash -> ~117 MB of gathers served
// by Infinity Cache (~12us stall, the measured gap).
// Partials are stored at the canonical round-7 index so the reduce
// kernel sums in the identical order -> bitwise-identical result.

constexpr int N = 2, H = 64, W = 64, D = 64, R = 3;
constexpr int WD  = W * D;
constexpr int HWD = H * W * D;
constexpr float INV_SXY  = 1.0f / 6.0f;
constexpr float LOG2E    = 1.4426950408889634f;
constexpr float C2       = 50.0f * LOG2E;   // 0.5*(1/0.1)^2 * log2(e)
constexpr int GBLOCKS = N * H * (W / 16);   // 512 spatial blocks
constexpr int NBLOCKS = 4 * GBLOCKS;        // x4 offset groups = 2048

__device__ __forceinline__ float exp2_fast(float x) {
    return __builtin_amdgcn_exp2f(x);       // v_exp_f32
}

// One offset group: 6 pairs, fully unrolled, loads batched before compute.
template <int DI0, int DJ0, int DI1, int DJ1, int DI2, int DJ2,
          int DI3, int DJ3, int DI4, int DJ4, int DI5, int DJ5>
__device__ __forceinline__ float group_sum(
    const float* __restrict__ sb, const float* __restrict__ y0b,
    int cidx, int h, int w,
    const float scv[4], const float bv[4]) {
    constexpr int DI[6] = {DI0, DI1, DI2, DI3, DI4, DI5};
    constexpr int DJ[6] = {DJ0, DJ1, DJ2, DJ3, DJ4, DJ5};

    bool   vld[6];
    float4 sn[6], an[6];

    // Phase 1: addresses + all 12 loads, no control flow in between.
    #pragma unroll
    for (int p = 0; p < 6; ++p) {
        const bool v = ((unsigned)(h + DI[p]) < (unsigned)H) &
                       ((unsigned)(w + DJ[p]) < (unsigned)W);
        vld[p] = v;
        const int off = v ? (DI[p] * WD + DJ[p] * D) : 0;  // clamp -> center
        sn[p] = *(const float4*)(sb  + cidx + off);
        an[p] = *(const float4*)(y0b + cidx + off);
    }

    // Phase 2: compute. Invalid pairs get A2 = -1e30 -> exp2 -> 0.
    float acc = 0.0f;
    #pragma unroll
    for (int p = 0; p < 6; ++p) {
        constexpr float d2[6] = {
            (float)(DI0 * DI0 + DJ0 * DJ0), (float)(DI1 * DI1 + DJ1 * DJ1),
            (float)(DI2 * DI2 + DJ2 * DJ2), (float)(DI3 * DI3 + DJ3 * DJ3),
            (float)(DI4 * DI4 + DJ4 * DJ4), (float)(DI5 * DI5 + DJ5 * DJ5)};
        const float A2  = -0.5f * d2[p] * (INV_SXY * INV_SXY) * LOG2E;
        const float A2e = vld[p] ? A2 : -1e30f;
        const float snv[4] = {sn[p].x, sn[p].y, sn[p].z, sn[p].w};
        const float anv[4] = {an[p].x, an[p].y, an[p].z, an[p].w};
        #pragma unroll
        for (int j = 0; j < 4; ++j) {
            const float dsr = snv[j] - scv[j];
            const float k   = exp2_fast(__builtin_fmaf(-C2 * dsr, dsr, A2e));
            const float ab  = anv[j] * bv[j];
            acc += k * (anv[j] + bv[j] - 2.0f * ab);
        }
    }
    return acc;
}

__global__ __launch_bounds__(256) void crf_partial(
    const float* __restrict__ y,   // (N,2,H,W,D) -- only channel 0 read
    const float* __restrict__ s,   // (N,1,H,W,D)
    float* __restrict__ partial) {
    const int tid   = threadIdx.x;
    const int d0    = (tid & 15) << 2;
    const int wlane = tid >> 4;
    const int bid   = blockIdx.x;

    // --- XCD-slab remap -------------------------------------------------
    // xcd = bid & 7 (dispatch round-robin). Each XCD owns h-slab
    // [8*xcd, 8*xcd+8) for both n -> ~720 KB working set, L2-resident.
    const int xcd    = bid & 7;
    const int r      = bid >> 3;          // 0..255 within XCD
    const int g      = r & 3;             // offset group 0..3
    const int wstrip = (r >> 2) & 3;
    const int h_loc  = (r >> 4) & 7;
    const int n      = r >> 7;
    const int h      = (xcd << 3) + h_loc;
    const int w      = (wstrip << 4) + wlane;
    // Canonical (round-7) partial index: reduce order stays bitwise-equal.
    const int pidx   = (g << 9) | (n << 8) | (h << 2) | wstrip;
    // --------------------------------------------------------------------

    const float* sb  = s + (size_t)n * HWD;
    const float* y0b = y + (size_t)n * (2 * HWD);

    const int cidx = h * WD + w * D + d0;
    const float4 sc4 = *(const float4*)(sb  + cidx);
    const float4 b4  = *(const float4*)(y0b + cidx);
    const float scv[4] = {sc4.x, sc4.y, sc4.z, sc4.w};
    const float bv[4]  = {b4.x,  b4.y,  b4.z,  b4.w};

    float acc = 0.0f;
    float extra = 0.0f;
    if (g == 0) {
        acc = group_sum<0, 1, 0, 2, 0, 3, 1, -3, 1, -2, 1, -1>(
            sb, y0b, cidx, h, w, scv, bv);
        // OOB closed form (window truncation), group 0 only.
        const int nrows = min(h + R, H - 1) - max(h - R, 0) + 1;
        const int ncols = min(w + R, W - 1) - max(w - R, 0) + 1;
        const int oob = 49 - nrows * ncols;
        if (oob) {
            const float fh = (float)h * INV_SXY;
            const float fw = (float)w * INV_SXY;
            const float base2 = -0.5f * (fh * fh + fw * fw) * LOG2E;
            float koob = 0.0f;
            #pragma unroll
            for (int j = 0; j < 4; ++j)
                koob += exp2_fast(__builtin_fmaf(-C2 * scv[j], scv[j], base2));
            extra = (float)oob * koob;
        }
    } else if (g == 1) {
        acc = group_sum<1, 0, 1, 1, 1, 2, 1, 3, 2, -3, 2, -2>(
            sb, y0b, cidx, h, w, scv, bv);
    } else if (g == 2) {
        acc = group_sum<2, -1, 2, 0, 2, 1, 2, 2, 2, 3, 3, -3>(
            sb, y0b, cidx, h, w, scv, bv);
    } else {
        acc = group_sum<3, -2, 3, -1, 3, 0, 3, 1, 3, 2, 3, 3>(
            sb, y0b, cidx, h, w, scv, bv);
    }

    float part = 2.0f * acc + extra;

    #pragma unroll
    for (int off = 32; off; off >>= 1)
        part += __shfl_down(part, off, 64);

    __shared__ float wsum[4];
    if ((tid & 63) == 0) wsum[tid >> 6] = part;
    __syncthreads();
    if (tid == 0) partial[pidx] = wsum[0] + wsum[1] + wsum[2] + wsum[3];
}

__global__ __launch_bounds__(256) void reduce_partials(
    const float* __restrict__ partial, float* __restrict__ out) {
    const int tid = threadIdx.x;
    float v = 0.0f;
    #pragma unroll
    for (int i = 0; i < NBLOCKS / 256; ++i)
        v += partial[tid + i * 256];
    #pragma unroll
    for (int off = 32; off; off >>= 1)
        v += __shfl_down(v, off, 64);
    __shared__ float wsum[4];
    if ((tid & 63) == 0) wsum[tid >> 6] = v;
    __syncthreads();
    if (tid == 0)
        out[0] = (wsum[0] + wsum[1] + wsum[2] + wsum[3]) *
                 (1.0f / (float)(N * D * H * W));
}

extern "C" void kernel_launch(void* const* d_in, const int* in_sizes, int n_in,
                              void* d_out, int out_size, void* d_ws, size_t ws_size,
                              hipStream_t stream) {
    const float* y = (const float*)d_in[0];
    const float* s = (const float*)d_in[1];
    float* partial = (float*)d_ws;   // NBLOCKS floats, all written before read

    crf_partial<<<dim3(NBLOCKS), dim3(256), 0, stream>>>(y, s, partial);
    reduce_partials<<<dim3(1), dim3(256), 0, stream>>>(partial, (float*)d_out);
}